// Round 7
// baseline (258.653 us; speedup 1.0000x reference)
//
#include <hip/hip_runtime.h>
#include <hip/hip_cooperative_groups.h>
#include <math.h>

namespace cg = cooperative_groups;

#define BG 64
#define NN 2048
#define KK 1024
#define EE 4194304

// out layout (all float32, return order):
#define OFF_EI   8388608
#define OFF_BAT  16777216
#define OFF_PERM 16842752
#define OFF_SCR  16908288
#define OFF_MSK  16973824

#define NBLK 256
#define NTHR 1024

typedef unsigned long long u64;
typedef float f4v __attribute__((ext_vector_type(4)));
typedef int   i4v __attribute__((ext_vector_type(4)));

__device__ __forceinline__ void nt_store4(float a, float b, float c, float d, float* p) {
    f4v v = {a, b, c, d};
    __builtin_nontemporal_store(v, (f4v*)p);
}

// monotone float<->uint order map (ascending)
__device__ __forceinline__ unsigned ford(float f) {
    unsigned b = __float_as_uint(f);
    return (b & 0x80000000u) ? ~b : (b | 0x80000000u);
}
__device__ __forceinline__ float forddec(unsigned u) {
    unsigned b = (u & 0x80000000u) ? (u & 0x7FFFFFFFu) : ~u;
    return __uint_as_float(b);
}

// bitonic compare-exchange via cross-lane shuffle
__device__ __forceinline__ u64 regswap(u64 v, int elem_idx, int j, int k) {
    u64 p = __shfl_xor(v, j, 64);
    bool dir   = ((elem_idx & k) == 0);
    bool lower = ((elem_idx & j) == 0);
    return (dir == lower) ? (v > p ? v : p) : (v < p ? v : p);
}

__global__ __launch_bounds__(NTHR, 4) void fused_kernel(
    const float* __restrict__ x, const int* __restrict__ ei,
    const float* __restrict__ w, float* __restrict__ out,
    float* __restrict__ scores, int* __restrict__ perm_int,
    unsigned short* __restrict__ tab16, unsigned* __restrict__ maskbits)
{
    __shared__ u64 shbuf[NN + 32];   // 16.6 KB: sort keys+mw, later smask
    cg::grid_group grid = cg::this_grid();
    const int bid = blockIdx.x;
    const int t   = threadIdx.x;

    // ---------- phase 1: score = tanh((x.w)/||w||) ----------
    // bit-identical math to the proven score_kernel; only the node-independent
    // ||w|| reduction is hoisted (same ops, same order -> same bits).
    {
        const float2* x2 = (const float2*)x;
        const float2* w2 = (const float2*)w;
        int lane = t & 63;
        int wavg = bid * 16 + (t >> 6);       // 4096 waves
        float2 wv = w2[lane];
        float ww = wv.x * wv.x + wv.y * wv.y;
        #pragma unroll
        for (int off = 32; off >= 1; off >>= 1) ww += __shfl_xor(ww, off);
        int nbase = wavg * 32;                // 32 nodes per wave
        for (int n = 0; n < 32; ++n) {
            int node = nbase + n;
            float2 xv = x2[(size_t)node * 64 + lane];
            float dot = xv.x * wv.x + xv.y * wv.y;
            #pragma unroll
            for (int off = 32; off >= 1; off >>= 1) dot += __shfl_xor(dot, off);
            if (lane == 0) scores[node] = tanhf(dot / sqrtf(ww));
        }
    }
    __threadfence();
    grid.sync();

    // ---------- phase 2: blocks 0..63 sort; blocks 64..255 prefetch edges ----------
    if (bid < BG) {
        u64* keys = shbuf;
        unsigned* mw = (unsigned*)(shbuf + NN);
        const int b = bid;
        float s0 = scores[b * NN + t];
        float s1 = scores[b * NN + 1024 + t];
        u64 va = ((u64)ford(s0) << 32) | (unsigned)(NN - 1 - t);
        u64 vb = ((u64)ford(s1) << 32) | (unsigned)(NN - 1 - (1024 + t));

        #pragma unroll
        for (int k = 2; k <= 64; k <<= 1)
            #pragma unroll
            for (int j = k >> 1; j >= 1; j >>= 1) {
                va = regswap(va, t, j, k);
                vb = regswap(vb, 1024 + t, j, k);
            }

        keys[t] = va; keys[1024 + t] = vb;
        if (t < NN / 32) mw[t] = 0u;
        __syncthreads();

        for (int k = 128; k <= 2048; k <<= 1) {
            for (int j = k >> 1; j >= 64; j >>= 1) {
                int i = ((t & ~(j - 1)) << 1) | (t & (j - 1));
                int p = i | j;
                u64 A = keys[i], C = keys[p];
                bool sw = ((i & k) == 0) ? (A < C) : (A > C);
                if (sw) { keys[i] = C; keys[p] = A; }
                __syncthreads();
            }
            va = keys[t]; vb = keys[1024 + t];
            #pragma unroll
            for (int j = 32; j >= 1; j >>= 1) {
                va = regswap(va, t, j, k);
                vb = regswap(vb, 1024 + t, j, k);
            }
            if (k < 2048) {
                keys[t] = va; keys[1024 + t] = vb;
                __syncthreads();
            }
        }

        int idx  = NN - 1 - (int)(va & 0xFFFFFFFFu);
        float s  = forddec((unsigned)(va >> 32));
        int gid  = b * NN + idx;
        int row  = b * KK + t;
        perm_int[row]       = gid;
        tab16[gid]          = (unsigned short)row;  // full new id fits u16
        out[OFF_PERM + row] = (float)gid;
        out[OFF_SCR + row]  = s;
        out[OFF_BAT + row]  = (float)b;
        atomicOr(&mw[idx >> 5], 1u << (idx & 31));
        __syncthreads();
        if (t < NN / 32) maskbits[b * (NN / 32) + t] = mw[t];
    } else {
        // prefetch edge list into L2/L3 with cached loads (overlaps the sort)
        const i4v* e4 = (const i4v*)ei;
        const int total4 = 2 * EE / 4;           // 2,097,152 int4
        int tid = (bid - BG) * NTHR + t;         // 0 .. 196607
        int acc = 0;
        for (size_t i = tid; i < (size_t)total4; i += (size_t)(NBLK - BG) * NTHR) {
            i4v v = e4[i];
            acc ^= v[0] ^ v[1] ^ v[2] ^ v[3];
        }
        asm volatile("" :: "v"(acc));            // keep loads live, no DCE
    }
    __threadfence();
    grid.sync();

    // ---------- phase 3: edge relabel+mask (LDS bitmask) + x gather ----------
    unsigned* smask = (unsigned*)shbuf;          // 16 KB
    {
        const uint4* mb4 = (const uint4*)maskbits;
        ((uint4*)smask)[t] = mb4[t];
        __syncthreads();
    }
    // edge half: each block handles 4096 int4 per array (16384 edges)
    {
        const int* e0 = ei;
        const int* e1 = ei + EE;
        float* oe0 = out + OFF_EI;
        float* oe1 = out + OFF_EI + EE;
        float* om  = out + OFF_MSK;
        size_t eb = (size_t)bid * 4096 + t;
        i4v r[4], c[4];
        #pragma unroll
        for (int u = 0; u < 4; ++u) {
            r[u] = ((const i4v*)e0)[eb + u * 1024];   // cached: L3-hot from prefetch
            c[u] = ((const i4v*)e1)[eb + u * 1024];
        }
        #pragma unroll
        for (int u = 0; u < 4; ++u) {
            size_t i = eb + u * 1024;
            float er[4], ec[4], em[4];
            #pragma unroll
            for (int q = 0; q < 4; ++q) {
                int rq = r[u][q], cq = c[u][q];
                unsigned m = (smask[(unsigned)rq >> 5] >> (rq & 31)) &
                             (smask[(unsigned)cq >> 5] >> (cq & 31)) & 1u;
                float nr = 0.0f, nc = 0.0f;
                if (m) {
                    nr = (float)tab16[rq];
                    nc = (float)tab16[cq];
                }
                er[q] = nr; ec[q] = nc; em[q] = m ? 1.0f : 0.0f;
            }
            nt_store4(er[0], er[1], er[2], er[3], oe0 + 4 * i);
            nt_store4(ec[0], ec[1], ec[2], ec[3], oe1 + 4 * i);
            nt_store4(em[0], em[1], em[2], em[3], om  + 4 * i);
        }
    }
    // gather half: 256 rows/block, 8 rows/thread as 2 passes of 4 (proven depth)
    {
        const float4* x4 = (const float4*)x;
        int lane = t & 31;
        int grp  = t >> 5;                        // 0..31
        #pragma unroll
        for (int pass = 0; pass < 2; ++pass) {
            int g[4]; float s[4];
            #pragma unroll
            for (int p = 0; p < 4; ++p) {
                int row = bid * 256 + grp + (pass * 4 + p) * 32;
                g[p] = perm_int[row];
                s[p] = out[OFF_SCR + row];
            }
            float4 v[4];
            #pragma unroll
            for (int p = 0; p < 4; ++p)
                v[p] = x4[(size_t)g[p] * 32 + lane];
            #pragma unroll
            for (int p = 0; p < 4; ++p) {
                int row = bid * 256 + grp + (pass * 4 + p) * 32;
                nt_store4(v[p].x * s[p], v[p].y * s[p], v[p].z * s[p], v[p].w * s[p],
                          out + ((size_t)row * 32 + lane) * 4);
            }
        }
    }
}

extern "C" void kernel_launch(void* const* d_in, const int* in_sizes, int n_in,
                              void* d_out, int out_size, void* d_ws, size_t ws_size,
                              hipStream_t stream)
{
    const float* x  = (const float*)d_in[0];   // [B*N, D]
    const int*   ei = (const int*)d_in[1];     // [2, E]
    const float* w  = (const float*)d_in[3];   // [D]
    float* out = (float*)d_out;

    // ws layout: scores f32[B*N] | perm_int i32[B*K] | tab16 u16[B*N] | maskbits u32[B*N/32]
    float*          scores   = (float*)d_ws;
    int*            perm_i   = (int*)d_ws + BG * NN;
    unsigned short* tab16    = (unsigned short*)((char*)d_ws + (BG * NN + BG * KK) * 4);
    unsigned*       maskbits = (unsigned*)((char*)d_ws + (BG * NN + BG * KK) * 4 + BG * NN * 2);

    void* args[] = { (void*)&x, (void*)&ei, (void*)&w, (void*)&out,
                     (void*)&scores, (void*)&perm_i, (void*)&tab16, (void*)&maskbits };
    hipLaunchCooperativeKernel((const void*)fused_kernel,
                               dim3(NBLK), dim3(NTHR), args, 0, stream);
}

// Round 8
// 70.438 us; speedup vs baseline: 3.6721x; 3.6721x over previous
//
#include <hip/hip_runtime.h>
#include <math.h>

#define BG 64
#define NN 2048
#define DD 128
#define KK 1024
#define EE 4194304

// out layout (all float32, return order):
#define OFF_EI   8388608
#define OFF_BAT  16777216
#define OFF_PERM 16842752
#define OFF_SCR  16908288
#define OFF_MSK  16973824

#define EDGE_BLOCKS   1024   // E / (256*16)
#define GATHER_BLOCKS 2048   // B*K / 32

typedef unsigned long long u64;
typedef float f4v __attribute__((ext_vector_type(4)));
typedef int   i4v __attribute__((ext_vector_type(4)));

__device__ __forceinline__ void nt_store4(float a, float b, float c, float d, float* p) {
    f4v v = {a, b, c, d};
    __builtin_nontemporal_store(v, (f4v*)p);
}

// ---------- kernel 1: score = tanh((x.w)/||w||), one wave per node ----------
// (kept byte-identical: its rounding defines the top-k tie behavior)
__global__ __launch_bounds__(256) void score_kernel(
    const float2* __restrict__ x2, const float2* __restrict__ w2,
    float* __restrict__ scores)
{
    int node = (blockIdx.x * 256 + threadIdx.x) >> 6;
    int lane = threadIdx.x & 63;
    float2 xv = x2[(size_t)node * 64 + lane];
    float2 wv = w2[lane];
    float dot = xv.x * wv.x + xv.y * wv.y;
    float ww  = wv.x * wv.x + wv.y * wv.y;
    #pragma unroll
    for (int off = 32; off >= 1; off >>= 1) {
        dot += __shfl_xor(dot, off);
        ww  += __shfl_xor(ww, off);
    }
    if (lane == 0) scores[node] = tanhf(dot / sqrtf(ww));
}

// monotone float<->uint order map (ascending)
__device__ __forceinline__ unsigned ford(float f) {
    unsigned b = __float_as_uint(f);
    return (b & 0x80000000u) ? ~b : (b | 0x80000000u);
}
__device__ __forceinline__ float forddec(unsigned u) {
    unsigned b = (u & 0x80000000u) ? (u & 0x7FFFFFFFu) : ~u;
    return __uint_as_float(b);
}

// bitonic compare-exchange via cross-lane shuffle (element held in register)
__device__ __forceinline__ u64 regswap(u64 v, int elem_idx, int j, int k) {
    u64 p = __shfl_xor(v, j, 64);
    bool dir   = ((elem_idx & k) == 0);   // true -> descending region
    bool lower = ((elem_idx & j) == 0);
    return (dir == lower) ? (v > p ? v : p) : (v < p ? v : p);
}

// ---------- kernel 2: per-graph bitonic sort (desc score, asc idx ties) ----------
__global__ __launch_bounds__(1024) void sort_kernel(
    const float* __restrict__ scores,
    int* __restrict__ perm_int, unsigned short* __restrict__ tab16,
    unsigned* __restrict__ maskbits,
    float* __restrict__ out_batch, float* __restrict__ out_perm,
    float* __restrict__ out_score)
{
    __shared__ u64 keys[NN];
    __shared__ unsigned mw[NN / 32];
    const int b = blockIdx.x;
    const int t = threadIdx.x;

    float s0 = scores[b * NN + t];
    float s1 = scores[b * NN + 1024 + t];
    u64 va = ((u64)ford(s0) << 32) | (unsigned)(NN - 1 - t);
    u64 vb = ((u64)ford(s1) << 32) | (unsigned)(NN - 1 - (1024 + t));

    // stages k=2..64: entirely intra-wave, no barriers
    #pragma unroll
    for (int k = 2; k <= 64; k <<= 1)
        #pragma unroll
        for (int j = k >> 1; j >= 1; j >>= 1) {
            va = regswap(va, t, j, k);
            vb = regswap(vb, 1024 + t, j, k);
        }

    keys[t] = va; keys[1024 + t] = vb;
    if (t < NN / 32) mw[t] = 0u;
    __syncthreads();

    for (int k = 128; k <= 2048; k <<= 1) {
        for (int j = k >> 1; j >= 64; j >>= 1) {
            int i = ((t & ~(j - 1)) << 1) | (t & (j - 1));
            int p = i | j;
            u64 A = keys[i], C = keys[p];
            bool sw = ((i & k) == 0) ? (A < C) : (A > C);
            if (sw) { keys[i] = C; keys[p] = A; }
            __syncthreads();
        }
        va = keys[t]; vb = keys[1024 + t];
        #pragma unroll
        for (int j = 32; j >= 1; j >>= 1) {
            va = regswap(va, t, j, k);
            vb = regswap(vb, 1024 + t, j, k);
        }
        if (k < 2048) {
            keys[t] = va; keys[1024 + t] = vb;
            __syncthreads();
        }
    }

    int idx  = NN - 1 - (int)(va & 0xFFFFFFFFu);
    float s  = forddec((unsigned)(va >> 32));
    int gid  = b * NN + idx;
    int row  = b * KK + t;
    perm_int[row]  = gid;
    tab16[gid]     = (unsigned short)row;   // full new id (b*K + rank <= 65535)
    out_perm[row]  = (float)gid;
    out_score[row] = s;
    out_batch[row] = (float)b;
    atomicOr(&mw[idx >> 5], 1u << (idx & 31));
    __syncthreads();
    if (t < NN / 32) maskbits[b * (NN / 32) + t] = mw[t];
}

// ---------- kernel 3a: edge relabel+mask (LDS bitmask), 16 edges/thread ----------
__global__ __launch_bounds__(256) void edge_kernel(
    const int* __restrict__ e0, const int* __restrict__ e1,
    const unsigned* __restrict__ mb, const unsigned short* __restrict__ tab,
    float* __restrict__ out)
{
    __shared__ unsigned smask[BG * NN / 32];   // 16 KB: kept-bit per node
    int t = threadIdx.x;
    // stage bitmask into LDS (coalesced, L2-resident source)
    const uint4* mb4 = (const uint4*)mb;
    uint4* sm4 = (uint4*)smask;
    #pragma unroll
    for (int u = 0; u < 4; ++u)
        sm4[u * 256 + t] = mb4[u * 256 + t];
    __syncthreads();

    float* oe0 = out + OFF_EI;
    float* oe1 = out + OFF_EI + EE;
    float* om  = out + OFF_MSK;

    size_t eb = (size_t)blockIdx.x * 1024 + t;    // in int4 units
    i4v r[4], c[4];
    #pragma unroll
    for (int u = 0; u < 4; ++u) {
        r[u] = __builtin_nontemporal_load((const i4v*)e0 + eb + u * 256);
        c[u] = __builtin_nontemporal_load((const i4v*)e1 + eb + u * 256);
    }
    #pragma unroll
    for (int u = 0; u < 4; ++u) {
        size_t i = eb + u * 256;
        float er[4], ec[4], em[4];
        #pragma unroll
        for (int q = 0; q < 4; ++q) {
            int rq = r[u][q], cq = c[u][q];
            unsigned m = (smask[(unsigned)rq >> 5] >> (rq & 31)) &
                         (smask[(unsigned)cq >> 5] >> (cq & 31)) & 1u;
            float nr = 0.0f, nc = 0.0f;
            if (m) {
                nr = (float)tab[rq];
                nc = (float)tab[cq];
            }
            er[q] = nr; ec[q] = nc; em[q] = m ? 1.0f : 0.0f;
        }
        nt_store4(er[0], er[1], er[2], er[3], oe0 + 4 * i);
        nt_store4(ec[0], ec[1], ec[2], ec[3], oe1 + 4 * i);
        nt_store4(em[0], em[1], em[2], em[3], om  + 4 * i);
    }
}

// ---------- kernel 3b: x gather, 4 rows/thread (R5-proven depth) ----------
__global__ __launch_bounds__(256) void gather_kernel(
    const float4* __restrict__ x4, const int* __restrict__ perm_int,
    const float* __restrict__ out_score, float* __restrict__ out)
{
    int t    = threadIdx.x;
    int lane = t & 31;
    int rbase = blockIdx.x * 32 + (t >> 5);   // 8 row-slots, 4 passes of stride 8
    int g[4]; float s[4];
    #pragma unroll
    for (int p = 0; p < 4; ++p) {
        int row = rbase + p * 8;
        g[p] = perm_int[row];
        s[p] = out_score[row];
    }
    float4 v[4];
    #pragma unroll
    for (int p = 0; p < 4; ++p)
        v[p] = x4[(size_t)g[p] * 32 + lane];
    #pragma unroll
    for (int p = 0; p < 4; ++p) {
        int row = rbase + p * 8;
        nt_store4(v[p].x * s[p], v[p].y * s[p], v[p].z * s[p], v[p].w * s[p],
                  out + ((size_t)row * 32 + lane) * 4);
    }
}

extern "C" void kernel_launch(void* const* d_in, const int* in_sizes, int n_in,
                              void* d_out, int out_size, void* d_ws, size_t ws_size,
                              hipStream_t stream)
{
    const float* x  = (const float*)d_in[0];   // [B*N, D]
    const int*   ei = (const int*)d_in[1];     // [2, E]
    const float* w  = (const float*)d_in[3];   // [D]
    float* out = (float*)d_out;

    // ws layout: scores f32[B*N] | perm_int i32[B*K] | tab16 u16[B*N] | maskbits u32[B*N/32]
    float*          scores   = (float*)d_ws;
    int*            perm_i   = (int*)d_ws + BG * NN;
    unsigned short* tab16    = (unsigned short*)((char*)d_ws + (BG * NN + BG * KK) * 4);
    unsigned*       maskbits = (unsigned*)((char*)d_ws + (BG * NN + BG * KK) * 4 + BG * NN * 2);

    score_kernel<<<BG * NN / 4, 256, 0, stream>>>(
        (const float2*)x, (const float2*)w, scores);

    sort_kernel<<<BG, 1024, 0, stream>>>(
        scores, perm_i, tab16, maskbits,
        out + OFF_BAT, out + OFF_PERM, out + OFF_SCR);

    edge_kernel<<<EDGE_BLOCKS, 256, 0, stream>>>(
        ei, ei + EE, maskbits, tab16, out);

    gather_kernel<<<GATHER_BLOCKS, 256, 0, stream>>>(
        (const float4*)x, perm_i, out + OFF_SCR, out);
}

// Round 9
// 63.649 us; speedup vs baseline: 4.0637x; 1.1067x over previous
//
#include <hip/hip_runtime.h>
#include <math.h>

#define BG 64
#define NN 2048
#define DD 128
#define KK 1024
#define EE 4194304

// out layout (all float32, return order):
#define OFF_EI   8388608
#define OFF_BAT  16777216
#define OFF_PERM 16842752
#define OFF_SCR  16908288
#define OFF_MSK  16973824

#define EDGE_BLOCKS   1024   // E / (256*16)
#define GATHER_BLOCKS 2048   // B*K / 32
#define SORT_BLOCKS   256    // 64 sort + 192 edge-prefetch

typedef unsigned long long u64;
typedef float f4v __attribute__((ext_vector_type(4)));
typedef int   i4v __attribute__((ext_vector_type(4)));

__device__ __forceinline__ void nt_store4(float a, float b, float c, float d, float* p) {
    f4v v = {a, b, c, d};
    __builtin_nontemporal_store(v, (f4v*)p);
}

// ---------- kernel 1: score = tanh((x.w)/||w||), one wave per node ----------
// (kept byte-identical: its rounding defines the top-k tie behavior)
__global__ __launch_bounds__(256) void score_kernel(
    const float2* __restrict__ x2, const float2* __restrict__ w2,
    float* __restrict__ scores)
{
    int node = (blockIdx.x * 256 + threadIdx.x) >> 6;
    int lane = threadIdx.x & 63;
    float2 xv = x2[(size_t)node * 64 + lane];
    float2 wv = w2[lane];
    float dot = xv.x * wv.x + xv.y * wv.y;
    float ww  = wv.x * wv.x + wv.y * wv.y;
    #pragma unroll
    for (int off = 32; off >= 1; off >>= 1) {
        dot += __shfl_xor(dot, off);
        ww  += __shfl_xor(ww, off);
    }
    if (lane == 0) scores[node] = tanhf(dot / sqrtf(ww));
}

// monotone float<->uint order map (ascending)
__device__ __forceinline__ unsigned ford(float f) {
    unsigned b = __float_as_uint(f);
    return (b & 0x80000000u) ? ~b : (b | 0x80000000u);
}
__device__ __forceinline__ float forddec(unsigned u) {
    unsigned b = (u & 0x80000000u) ? (u & 0x7FFFFFFFu) : ~u;
    return __uint_as_float(b);
}

// bitonic compare-exchange via cross-lane shuffle (element held in register)
__device__ __forceinline__ u64 regswap(u64 v, int elem_idx, int j, int k) {
    u64 p = __shfl_xor(v, j, 64);
    bool dir   = ((elem_idx & k) == 0);   // true -> descending region
    bool lower = ((elem_idx & j) == 0);
    return (dir == lower) ? (v > p ? v : p) : (v < p ? v : p);
}

// ---------- kernel 2: blocks 0..63 per-graph bitonic sort; 64..255 edge prefetch ----------
__global__ __launch_bounds__(1024) void sort_kernel(
    const float* __restrict__ scores, const int* __restrict__ ei,
    int* __restrict__ perm_int, unsigned short* __restrict__ tab16,
    unsigned* __restrict__ maskbits,
    float* __restrict__ out_batch, float* __restrict__ out_perm,
    float* __restrict__ out_score)
{
    const int b = blockIdx.x;
    const int t = threadIdx.x;

    if (b >= BG) {
        // warm edges into L2/L3 while the 64 sort blocks work (cached loads)
        const i4v* e4 = (const i4v*)ei;
        const size_t total4 = 2 * EE / 4;          // 2,097,152 int4
        size_t tid = (size_t)(b - BG) * 1024 + t;  // 0 .. 196607
        int acc = 0;
        for (size_t i = tid; i < total4; i += (size_t)(SORT_BLOCKS - BG) * 1024) {
            i4v v = e4[i];
            acc ^= v[0] ^ v[1] ^ v[2] ^ v[3];
        }
        asm volatile("" :: "v"(acc));              // keep loads live (no DCE)
        return;
    }

    __shared__ u64 keys[NN];
    __shared__ unsigned mw[NN / 32];

    float s0 = scores[b * NN + t];
    float s1 = scores[b * NN + 1024 + t];
    u64 va = ((u64)ford(s0) << 32) | (unsigned)(NN - 1 - t);
    u64 vb = ((u64)ford(s1) << 32) | (unsigned)(NN - 1 - (1024 + t));

    // stages k=2..64: entirely intra-wave, no barriers
    #pragma unroll
    for (int k = 2; k <= 64; k <<= 1)
        #pragma unroll
        for (int j = k >> 1; j >= 1; j >>= 1) {
            va = regswap(va, t, j, k);
            vb = regswap(vb, 1024 + t, j, k);
        }

    keys[t] = va; keys[1024 + t] = vb;
    if (t < NN / 32) mw[t] = 0u;
    __syncthreads();

    for (int k = 128; k <= 2048; k <<= 1) {
        for (int j = k >> 1; j >= 64; j >>= 1) {
            int i = ((t & ~(j - 1)) << 1) | (t & (j - 1));
            int p = i | j;
            u64 A = keys[i], C = keys[p];
            bool sw = ((i & k) == 0) ? (A < C) : (A > C);
            if (sw) { keys[i] = C; keys[p] = A; }
            __syncthreads();
        }
        va = keys[t]; vb = keys[1024 + t];
        #pragma unroll
        for (int j = 32; j >= 1; j >>= 1) {
            va = regswap(va, t, j, k);
            vb = regswap(vb, 1024 + t, j, k);
        }
        if (k < 2048) {
            keys[t] = va; keys[1024 + t] = vb;
            __syncthreads();
        }
    }

    int idx  = NN - 1 - (int)(va & 0xFFFFFFFFu);
    float s  = forddec((unsigned)(va >> 32));
    int gid  = b * NN + idx;
    int row  = b * KK + t;
    perm_int[row]  = gid;
    tab16[gid]     = (unsigned short)row;   // full new id (b*K + rank <= 65535)
    out_perm[row]  = (float)gid;
    out_score[row] = s;
    out_batch[row] = (float)b;
    atomicOr(&mw[idx >> 5], 1u << (idx & 31));
    __syncthreads();
    if (t < NN / 32) maskbits[b * (NN / 32) + t] = mw[t];
}

// ---------- fused kernel 3: edge relabel+mask (LDS bitmask) + x gather ----------
__global__ __launch_bounds__(256) void tail_kernel(
    const int* __restrict__ e0, const int* __restrict__ e1,
    const unsigned* __restrict__ mb, const unsigned short* __restrict__ tab,
    const float4* __restrict__ x4, const int* __restrict__ perm_int,
    const float* __restrict__ out_score, float* __restrict__ out)
{
    __shared__ unsigned smask[BG * NN / 32];   // 16 KB: kept-bit per node
    int bid = blockIdx.x;
    int t   = threadIdx.x;
    if (bid < EDGE_BLOCKS) {
        // stage bitmask into LDS (coalesced, L2-resident source)
        const uint4* mb4 = (const uint4*)mb;
        uint4* sm4 = (uint4*)smask;
        #pragma unroll
        for (int u = 0; u < 4; ++u)
            sm4[u * 256 + t] = mb4[u * 256 + t];
        __syncthreads();

        float* oe0 = out + OFF_EI;
        float* oe1 = out + OFF_EI + EE;
        float* om  = out + OFF_MSK;

        size_t eb = (size_t)bid * 1024 + t;    // in int4 units
        i4v r[4], c[4];
        #pragma unroll
        for (int u = 0; u < 4; ++u) {
            r[u] = ((const i4v*)e0)[eb + u * 256];   // cached: L3-warm from prefetch
            c[u] = ((const i4v*)e1)[eb + u * 256];
        }
        #pragma unroll
        for (int u = 0; u < 4; ++u) {
            size_t i = eb + u * 256;
            float er[4], ec[4], em[4];
            #pragma unroll
            for (int q = 0; q < 4; ++q) {
                int rq = r[u][q], cq = c[u][q];
                unsigned m = (smask[(unsigned)rq >> 5] >> (rq & 31)) &
                             (smask[(unsigned)cq >> 5] >> (cq & 31)) & 1u;
                float nr = 0.0f, nc = 0.0f;
                if (m) {
                    nr = (float)tab[rq];
                    nc = (float)tab[cq];
                }
                er[q] = nr; ec[q] = nc; em[q] = m ? 1.0f : 0.0f;
            }
            nt_store4(er[0], er[1], er[2], er[3], oe0 + 4 * i);
            nt_store4(ec[0], ec[1], ec[2], ec[3], oe1 + 4 * i);
            nt_store4(em[0], em[1], em[2], em[3], om  + 4 * i);
        }
    } else {
        int gb   = bid - EDGE_BLOCKS;
        int lane = t & 31;
        int rbase = gb * 32 + (t >> 5);        // 8 row-slots, 4 passes of stride 8
        int g[4]; float s[4];
        #pragma unroll
        for (int p = 0; p < 4; ++p) {
            int row = rbase + p * 8;
            g[p] = perm_int[row];
            s[p] = out_score[row];
        }
        float4 v[4];
        #pragma unroll
        for (int p = 0; p < 4; ++p)
            v[p] = x4[(size_t)g[p] * 32 + lane];
        #pragma unroll
        for (int p = 0; p < 4; ++p) {
            int row = rbase + p * 8;
            nt_store4(v[p].x * s[p], v[p].y * s[p], v[p].z * s[p], v[p].w * s[p],
                      out + ((size_t)row * 32 + lane) * 4);
        }
    }
}

extern "C" void kernel_launch(void* const* d_in, const int* in_sizes, int n_in,
                              void* d_out, int out_size, void* d_ws, size_t ws_size,
                              hipStream_t stream)
{
    const float* x  = (const float*)d_in[0];   // [B*N, D]
    const int*   ei = (const int*)d_in[1];     // [2, E]
    const float* w  = (const float*)d_in[3];   // [D]
    float* out = (float*)d_out;

    // ws layout: scores f32[B*N] | perm_int i32[B*K] | tab16 u16[B*N] | maskbits u32[B*N/32]
    float*          scores   = (float*)d_ws;
    int*            perm_i   = (int*)d_ws + BG * NN;
    unsigned short* tab16    = (unsigned short*)((char*)d_ws + (BG * NN + BG * KK) * 4);
    unsigned*       maskbits = (unsigned*)((char*)d_ws + (BG * NN + BG * KK) * 4 + BG * NN * 2);

    score_kernel<<<BG * NN / 4, 256, 0, stream>>>(
        (const float2*)x, (const float2*)w, scores);

    sort_kernel<<<SORT_BLOCKS, 1024, 0, stream>>>(
        scores, ei, perm_i, tab16, maskbits,
        out + OFF_BAT, out + OFF_PERM, out + OFF_SCR);

    tail_kernel<<<EDGE_BLOCKS + GATHER_BLOCKS, 256, 0, stream>>>(
        ei, ei + EE, maskbits, tab16,
        (const float4*)x, perm_i, out + OFF_SCR, out);
}

// Round 10
// 63.089 us; speedup vs baseline: 4.0998x; 1.0089x over previous
//
#include <hip/hip_runtime.h>
#include <math.h>

#define BG 64
#define NN 2048
#define DD 128
#define KK 1024
#define EE 4194304

// out layout (all float32, return order):
#define OFF_EI   8388608
#define OFF_BAT  16777216
#define OFF_PERM 16842752
#define OFF_SCR  16908288
#define OFF_MSK  16973824

#define EDGE_BLOCKS   1024   // E / (256*16)
#define GATHER_BLOCKS 2048   // B*K / 32
#define SORT_BLOCKS   256    // 64 sort + 192 edge-prefetch

typedef unsigned long long u64;
typedef float f4v __attribute__((ext_vector_type(4)));
typedef int   i4v __attribute__((ext_vector_type(4)));

__device__ __forceinline__ void nt_store4(float a, float b, float c, float d, float* p) {
    f4v v = {a, b, c, d};
    __builtin_nontemporal_store(v, (f4v*)p);
}

// ---------- kernel 1: score = tanh((x.w)/||w||), one wave per node ----------
// (kept byte-identical: its rounding defines the top-k tie behavior)
__global__ __launch_bounds__(256) void score_kernel(
    const float2* __restrict__ x2, const float2* __restrict__ w2,
    float* __restrict__ scores)
{
    int node = (blockIdx.x * 256 + threadIdx.x) >> 6;
    int lane = threadIdx.x & 63;
    float2 xv = x2[(size_t)node * 64 + lane];
    float2 wv = w2[lane];
    float dot = xv.x * wv.x + xv.y * wv.y;
    float ww  = wv.x * wv.x + wv.y * wv.y;
    #pragma unroll
    for (int off = 32; off >= 1; off >>= 1) {
        dot += __shfl_xor(dot, off);
        ww  += __shfl_xor(ww, off);
    }
    if (lane == 0) scores[node] = tanhf(dot / sqrtf(ww));
}

// monotone float<->uint order map (ascending)
__device__ __forceinline__ unsigned ford(float f) {
    unsigned b = __float_as_uint(f);
    return (b & 0x80000000u) ? ~b : (b | 0x80000000u);
}
__device__ __forceinline__ float forddec(unsigned u) {
    unsigned b = (u & 0x80000000u) ? (u & 0x7FFFFFFFu) : ~u;
    return __uint_as_float(b);
}

// bitonic compare-exchange via cross-lane shuffle (element held in register)
__device__ __forceinline__ u64 regswap(u64 v, int elem_idx, int j, int k) {
    u64 p = __shfl_xor(v, j, 64);
    bool dir   = ((elem_idx & k) == 0);   // true -> descending region
    bool lower = ((elem_idx & j) == 0);
    return (dir == lower) ? (v > p ? v : p) : (v < p ? v : p);
}

// ---------- kernel 2: blocks 0..63 per-graph bitonic sort; 64..255 edge prefetch ----------
__global__ __launch_bounds__(1024) void sort_kernel(
    const float* __restrict__ scores, const int* __restrict__ ei,
    int* __restrict__ perm_int, unsigned short* __restrict__ tab16,
    unsigned* __restrict__ maskbits,
    float* __restrict__ out_batch, float* __restrict__ out_perm,
    float* __restrict__ out_score)
{
    const int b = blockIdx.x;
    const int t = threadIdx.x;

    if (b >= BG) {
        // warm edges into L2/L3 while the 64 sort blocks work (cached loads)
        const i4v* e4 = (const i4v*)ei;
        const size_t total4 = 2 * EE / 4;          // 2,097,152 int4
        size_t tid = (size_t)(b - BG) * 1024 + t;  // 0 .. 196607
        int acc = 0;
        for (size_t i = tid; i < total4; i += (size_t)(SORT_BLOCKS - BG) * 1024) {
            i4v v = e4[i];
            acc ^= v[0] ^ v[1] ^ v[2] ^ v[3];
        }
        asm volatile("" :: "v"(acc));              // keep loads live (no DCE)
        return;
    }

    __shared__ u64 keys[NN];
    __shared__ unsigned mw[NN / 32];

    float s0 = scores[b * NN + t];
    float s1 = scores[b * NN + 1024 + t];
    u64 va = ((u64)ford(s0) << 32) | (unsigned)(NN - 1 - t);
    u64 vb = ((u64)ford(s1) << 32) | (unsigned)(NN - 1 - (1024 + t));

    // stages k=2..64: entirely intra-wave, no barriers
    #pragma unroll
    for (int k = 2; k <= 64; k <<= 1)
        #pragma unroll
        for (int j = k >> 1; j >= 1; j >>= 1) {
            va = regswap(va, t, j, k);
            vb = regswap(vb, 1024 + t, j, k);
        }

    keys[t] = va; keys[1024 + t] = vb;
    if (t < NN / 32) mw[t] = 0u;
    __syncthreads();

    for (int k = 128; k <= 2048; k <<= 1) {
        for (int j = k >> 1; j >= 64; j >>= 1) {
            int i = ((t & ~(j - 1)) << 1) | (t & (j - 1));
            int p = i | j;
            u64 A = keys[i], C = keys[p];
            bool sw = ((i & k) == 0) ? (A < C) : (A > C);
            if (sw) { keys[i] = C; keys[p] = A; }
            __syncthreads();
        }
        va = keys[t]; vb = keys[1024 + t];
        #pragma unroll
        for (int j = 32; j >= 1; j >>= 1) {
            va = regswap(va, t, j, k);
            vb = regswap(vb, 1024 + t, j, k);
        }
        if (k < 2048) {
            keys[t] = va; keys[1024 + t] = vb;
            __syncthreads();
        }
    }

    int idx  = NN - 1 - (int)(va & 0xFFFFFFFFu);
    float s  = forddec((unsigned)(va >> 32));
    int gid  = b * NN + idx;
    int row  = b * KK + t;
    perm_int[row]  = gid;
    tab16[gid]     = (unsigned short)row;   // full new id (b*K + rank <= 65535)
    out_perm[row]  = (float)gid;
    out_score[row] = s;
    out_batch[row] = (float)b;
    atomicOr(&mw[idx >> 5], 1u << (idx & 31));
    __syncthreads();
    if (t < NN / 32) maskbits[b * (NN / 32) + t] = mw[t];
}

// ---------- fused kernel 3: edge relabel+mask (LDS bitmask) + x gather ----------
__global__ __launch_bounds__(256) void tail_kernel(
    const int* __restrict__ e0, const int* __restrict__ e1,
    const unsigned* __restrict__ mb, const unsigned short* __restrict__ tab,
    const float4* __restrict__ x4, const int* __restrict__ perm_int,
    const float* __restrict__ out_score, float* __restrict__ out)
{
    __shared__ unsigned smask[BG * NN / 32];   // 16 KB: kept-bit per node
    int bid = blockIdx.x;
    int t   = threadIdx.x;
    if (bid < EDGE_BLOCKS) {
        // stage bitmask into LDS (coalesced, L2-resident source)
        const uint4* mb4 = (const uint4*)mb;
        uint4* sm4 = (uint4*)smask;
        #pragma unroll
        for (int u = 0; u < 4; ++u)
            sm4[u * 256 + t] = mb4[u * 256 + t];
        __syncthreads();

        float* oe0 = out + OFF_EI;
        float* oe1 = out + OFF_EI + EE;
        float* om  = out + OFF_MSK;

        size_t eb = (size_t)bid * 1024 + t;    // in int4 units
        i4v r[4], c[4];
        #pragma unroll
        for (int u = 0; u < 4; ++u) {
            r[u] = ((const i4v*)e0)[eb + u * 256];   // cached: L3-warm from prefetch
            c[u] = ((const i4v*)e1)[eb + u * 256];
        }
        #pragma unroll
        for (int u = 0; u < 4; ++u) {
            size_t i = eb + u * 256;
            float er[4], ec[4], em[4];
            #pragma unroll
            for (int q = 0; q < 4; ++q) {
                int rq = r[u][q], cq = c[u][q];
                unsigned m = (smask[(unsigned)rq >> 5] >> (rq & 31)) &
                             (smask[(unsigned)cq >> 5] >> (cq & 31)) & 1u;
                float nr = 0.0f, nc = 0.0f;
                if (m) {
                    nr = (float)tab[rq];
                    nc = (float)tab[cq];
                }
                er[q] = nr; ec[q] = nc; em[q] = m ? 1.0f : 0.0f;
            }
            nt_store4(er[0], er[1], er[2], er[3], oe0 + 4 * i);
            nt_store4(ec[0], ec[1], ec[2], ec[3], oe1 + 4 * i);
            nt_store4(em[0], em[1], em[2], em[3], om  + 4 * i);
        }
    } else {
        int gb   = bid - EDGE_BLOCKS;
        int lane = t & 31;
        int rbase = gb * 32 + (t >> 5);        // 8 row-slots, 4 passes of stride 8
        int g[4]; float s[4];
        #pragma unroll
        for (int p = 0; p < 4; ++p) {
            int row = rbase + p * 8;
            g[p] = perm_int[row];
            s[p] = out_score[row];
        }
        float4 v[4];
        #pragma unroll
        for (int p = 0; p < 4; ++p)
            v[p] = x4[(size_t)g[p] * 32 + lane];
        #pragma unroll
        for (int p = 0; p < 4; ++p) {
            int row = rbase + p * 8;
            nt_store4(v[p].x * s[p], v[p].y * s[p], v[p].z * s[p], v[p].w * s[p],
                      out + ((size_t)row * 32 + lane) * 4);
        }
    }
}

extern "C" void kernel_launch(void* const* d_in, const int* in_sizes, int n_in,
                              void* d_out, int out_size, void* d_ws, size_t ws_size,
                              hipStream_t stream)
{
    const float* x  = (const float*)d_in[0];   // [B*N, D]
    const int*   ei = (const int*)d_in[1];     // [2, E]
    const float* w  = (const float*)d_in[3];   // [D]
    float* out = (float*)d_out;

    // ws layout: scores f32[B*N] | perm_int i32[B*K] | tab16 u16[B*N] | maskbits u32[B*N/32]
    float*          scores   = (float*)d_ws;
    int*            perm_i   = (int*)d_ws + BG * NN;
    unsigned short* tab16    = (unsigned short*)((char*)d_ws + (BG * NN + BG * KK) * 4);
    unsigned*       maskbits = (unsigned*)((char*)d_ws + (BG * NN + BG * KK) * 4 + BG * NN * 2);

    score_kernel<<<BG * NN / 4, 256, 0, stream>>>(
        (const float2*)x, (const float2*)w, scores);

    sort_kernel<<<SORT_BLOCKS, 1024, 0, stream>>>(
        scores, ei, perm_i, tab16, maskbits,
        out + OFF_BAT, out + OFF_PERM, out + OFF_SCR);

    tail_kernel<<<EDGE_BLOCKS + GATHER_BLOCKS, 256, 0, stream>>>(
        ei, ei + EE, maskbits, tab16,
        (const float4*)x, perm_i, out + OFF_SCR, out);
}